// Round 1
// baseline (1229.049 us; speedup 1.0000x reference)
//
#include <hip/hip_runtime.h>
#include <math.h>

// Problem constants (fixed by setup_inputs: B=4, D=128, T=8, P=4096)
#define BB 4
#define DD 128
#define TT 8
#define PP 4096
#define KK 10
#define NT 7              // T-1 frame pairs
#define BP (BB*PP)        // 16384 points per frame across batch
#define NQ (NT*BP)        // 114688 total queries
#define NBLK_COS 896
#define QPB 128           // queries per block in cos kernel (NBLK_COS*QPB == NQ)

// Workspace layout (bytes, all 256-aligned)
#define OFF_FEATT 0u                 // NQ*DD floats  = 58,720,256 B
#define OFF_IDX   58720256u          // NQ*KK ints    =  4,587,520 B
#define OFF_DV    63307776u          // NQ floats     =    458,752 B
#define OFF_NORM  63766528u          // NQ floats     =    458,752 B
#define OFF_SCALE 64225280u          // NT floats (padded to 256)
#define OFF_PART  64225536u          // NBLK_COS floats

// ---------------------------------------------------------------------------
// Kernel A: exact top-10 KNN (stable, matches jax.lax.top_k) + disp variance
// ---------------------------------------------------------------------------
__global__ __launch_bounds__(256) void knn_disp_kernel(
    const float* __restrict__ pts4, int* __restrict__ idx_out,
    float* __restrict__ dv_out) {
  __shared__ float4 pts[PP];  // (x,y,z,xx) — 64 KB
  const int b = blockIdx.y, t = blockIdx.z;
  const float4* src0 = (const float4*)pts4 + ((size_t)(b * TT + t) * PP);
  const float4* src1 = src0 + PP;  // frame t+1

  for (int i = threadIdx.x; i < PP; i += 256) {
    float4 v = src0[i];
    float xx = fmaf(v.x, v.x, fmaf(v.y, v.y, v.z * v.z));
    pts[i] = make_float4(v.x, v.y, v.z, xx);
  }
  __syncthreads();

  const int p = blockIdx.x * 256 + threadIdx.x;
  const float4 q = pts[p];

  float best[KK];
  int bidx[KK];
#pragma unroll
  for (int i = 0; i < KK; ++i) { best[i] = -INFINITY; bidx[i] = 0; }

  // Scan candidates in ascending index order. Strict '>' on entry and on
  // bubble-up exactly reproduces top_k's "equal values -> lower index first".
  for (int j = 0; j < PP; ++j) {
    float4 c = pts[j];  // broadcast LDS read (all lanes same address)
    float inner = fmaf(q.x, c.x, fmaf(q.y, c.y, q.z * c.z));
    float nd = 2.0f * inner - q.w - c.w;  // == 0 exactly when j == p
    if (nd > best[KK - 1]) {
      best[KK - 1] = nd; bidx[KK - 1] = j;
#pragma unroll
      for (int i = KK - 1; i > 0; --i) {
        if (best[i] > best[i - 1]) {
          float tv = best[i]; best[i] = best[i - 1]; best[i - 1] = tv;
          int ti = bidx[i]; bidx[i] = bidx[i - 1]; bidx[i - 1] = ti;
        }
      }
    }
  }

  // disp variance over neighbors (disp read from global; 2 MB slice is L2-hot)
  float4 a0 = src0[p], a1 = src1[p];
  const float dqx = a1.x - a0.x, dqy = a1.y - a0.y, dqz = a1.z - a0.z;
  float s = 0.0f;
#pragma unroll
  for (int k = 0; k < KK; ++k) {
    int j = bidx[k];
    float4 c0 = src0[j], c1 = src1[j];
    float dx = (c1.x - c0.x) - dqx;
    float dy = (c1.y - c0.y) - dqy;
    float dz = (c1.z - c0.z) - dqz;
    s += fmaf(dx, dx, fmaf(dy, dy, dz * dz));
  }

  const size_t g = (size_t)(t * BB + b) * PP + p;
  dv_out[g] = s * (1.0f / KK);
#pragma unroll
  for (int k = 0; k < KK; ++k) idx_out[g * KK + k] = bidx[k];
}

// ---------------------------------------------------------------------------
// Kernel B: transpose encoded[b][d][t*P+p] -> featT[t][b][p][d]  (t < NT)
// ---------------------------------------------------------------------------
__global__ __launch_bounds__(256) void transpose_kernel(
    const float* __restrict__ encoded, float* __restrict__ featT) {
  __shared__ float tile[32][33];
  const int slice = blockIdx.z;  // t*BB + b
  const int t = slice / BB, b = slice % BB;
  const int p0 = blockIdx.x * 32, d0 = blockIdx.y * 32;
  const int tx = threadIdx.x, ty = threadIdx.y;
#pragma unroll
  for (int r = 0; r < 4; ++r) {
    int d = d0 + ty + r * 8;
    tile[ty + r * 8][tx] =
        encoded[((size_t)(b * DD + d)) * (TT * PP) + (size_t)t * PP + p0 + tx];
  }
  __syncthreads();
#pragma unroll
  for (int r = 0; r < 4; ++r) {
    int p = p0 + ty + r * 8;
    featT[((size_t)slice * PP + p) * DD + d0 + tx] = tile[tx][ty + r * 8];
  }
}

// ---------------------------------------------------------------------------
// Kernel N: per-point feature L2 norms (wave per point)
// ---------------------------------------------------------------------------
__global__ __launch_bounds__(256) void norms_kernel(
    const float* __restrict__ featT, float* __restrict__ norms) {
  const int w = threadIdx.x >> 6, lane = threadIdx.x & 63;
  const int wid = blockIdx.x * 4 + w;
  for (int i = 0; i < 32; ++i) {
    const int g = wid * 32 + i;
    float2 f = *(const float2*)(featT + (size_t)g * DD + lane * 2);
    float part = fmaf(f.x, f.x, f.y * f.y);
#pragma unroll
    for (int o = 32; o > 0; o >>= 1) part += __shfl_xor(part, o);
    if (lane == 0) norms[g] = sqrtf(part);
  }
}

// ---------------------------------------------------------------------------
// Kernel C: exact lower-median per t via 4-pass radix select on float bits
// (disp_var >= 0, so uint32 order == float order)
// ---------------------------------------------------------------------------
__global__ __launch_bounds__(256) void median_kernel(
    const float* __restrict__ disp_var, float* __restrict__ scale) {
  const int t = blockIdx.x;
  const unsigned* u = (const unsigned*)(disp_var + (size_t)t * BP);
  __shared__ unsigned hist[256];
  __shared__ unsigned sh_prefix;
  __shared__ int sh_rank;
  if (threadIdx.x == 0) { sh_prefix = 0u; sh_rank = (BP - 1) >> 1; }
  __syncthreads();
  for (int pass = 0; pass < 4; ++pass) {
    const int shift = 24 - pass * 8;
    hist[threadIdx.x] = 0u;
    __syncthreads();
    const unsigned hmask = (pass == 0) ? 0u : (0xFFFFFFFFu << (shift + 8));
    const unsigned prefix = sh_prefix;
    for (int i = threadIdx.x; i < BP; i += 256) {
      unsigned v = u[i];
      if ((v & hmask) == prefix) atomicAdd(&hist[(v >> shift) & 255u], 1u);
    }
    __syncthreads();
    if (threadIdx.x == 0) {
      int rank = sh_rank;
      unsigned run = 0u;
      for (int c = 0; c < 256; ++c) {
        unsigned h = hist[c];
        if (run + h > (unsigned)rank) {
          sh_rank = rank - (int)run;
          sh_prefix = prefix | ((unsigned)c << shift);
          break;
        }
        run += h;
      }
    }
    __syncthreads();
  }
  if (threadIdx.x == 0) {
    float med = __uint_as_float(sh_prefix);
    scale[t] = fmaxf(med, 1e-6f);
  }
}

// ---------------------------------------------------------------------------
// Kernel D: cosine similarity + rigidity loss, deterministic block partials
// ---------------------------------------------------------------------------
__global__ __launch_bounds__(256) void cos_loss_kernel(
    const float* __restrict__ featT, const int* __restrict__ idxw,
    const float* __restrict__ norms, const float* __restrict__ dv,
    const float* __restrict__ scale, float* __restrict__ partial) {
  const int w = threadIdx.x >> 6, lane = threadIdx.x & 63;
  __shared__ float wsum[4];
  float acc = 0.0f;
  const int qbase = blockIdx.x * QPB + w * (QPB / 4);
  for (int i = 0; i < QPB / 4; ++i) {
    const int g = qbase + i;
    const int t = g / BP;           // BP = 16384 (power of two -> shift)
    const int rem = g - t * BP;
    const int p = rem & (PP - 1);
    const int slice = g - p;        // base of this (t,b) slice
    const float* fbase = featT + (size_t)g * DD;
    float2 fq = *(const float2*)(fbase + lane * 2);
    float nq = fmaxf(norms[g], 1e-8f);
    const int* ip = idxw + (size_t)g * KK;
    float msum = 0.0f;
#pragma unroll
    for (int k = 0; k < KK; ++k) {
      int j = ip[k];
      const float* nb = featT + (size_t)(slice + j) * DD;
      float2 fn = *(const float2*)(nb + lane * 2);
      float part = fmaf(fq.x, fn.x, fq.y * fn.y);
#pragma unroll
      for (int o = 32; o > 0; o >>= 1) part += __shfl_xor(part, o);
      float nn = fmaxf(norms[slice + j], 1e-8f);
      msum += part / (nq * nn);
    }
    float mean_sim = msum * (1.0f / KK);
    float rig = expf(-dv[g] / scale[t]);
    acc += rig * (1.0f - mean_sim);
  }
  if (lane == 0) wsum[w] = acc;
  __syncthreads();
  if (threadIdx.x == 0)
    partial[blockIdx.x] = (wsum[0] + wsum[1]) + (wsum[2] + wsum[3]);
}

// ---------------------------------------------------------------------------
// Kernel E: final deterministic reduce -> scalar loss
// ---------------------------------------------------------------------------
__global__ __launch_bounds__(256) void final_reduce_kernel(
    const float* __restrict__ partial, float* __restrict__ out) {
  __shared__ float sh[256];
  float s = 0.0f;
  for (int i = threadIdx.x; i < NBLK_COS; i += 256) s += partial[i];
  sh[threadIdx.x] = s;
  __syncthreads();
  for (int st = 128; st > 0; st >>= 1) {
    if (threadIdx.x < st) sh[threadIdx.x] += sh[threadIdx.x + st];
    __syncthreads();
  }
  if (threadIdx.x == 0) out[0] = sh[0] * (1.0f / (float)NQ);
}

extern "C" void kernel_launch(void* const* d_in, const int* in_sizes, int n_in,
                              void* d_out, int out_size, void* d_ws,
                              size_t ws_size, hipStream_t stream) {
  const float* encoded = (const float*)d_in[0];
  const float* pts4 = (const float*)d_in[1];
  char* ws = (char*)d_ws;
  float* featT = (float*)(ws + OFF_FEATT);
  int* idxw = (int*)(ws + OFF_IDX);
  float* dv = (float*)(ws + OFF_DV);
  float* norms = (float*)(ws + OFF_NORM);
  float* scale = (float*)(ws + OFF_SCALE);
  float* partial = (float*)(ws + OFF_PART);
  float* outp = (float*)d_out;

  knn_disp_kernel<<<dim3(PP / 256, BB, NT), 256, 0, stream>>>(pts4, idxw, dv);
  transpose_kernel<<<dim3(PP / 32, DD / 32, NT * BB), dim3(32, 8), 0, stream>>>(
      encoded, featT);
  norms_kernel<<<NBLK_COS, 256, 0, stream>>>(featT, norms);
  median_kernel<<<NT, 256, 0, stream>>>(dv, scale);
  cos_loss_kernel<<<NBLK_COS, 256, 0, stream>>>(featT, idxw, norms, dv, scale,
                                                partial);
  final_reduce_kernel<<<1, 256, 0, stream>>>(partial, outp);
}